// Round 10
// baseline (697.571 us; speedup 1.0000x reference)
//
#include <hip/hip_runtime.h>
#include <cstdint>

typedef __bf16 bf16_t;
typedef bf16_t bf16x8 __attribute__((ext_vector_type(8)));
typedef bf16_t bf16x4 __attribute__((ext_vector_type(4)));
typedef float  floatx4 __attribute__((ext_vector_type(4)));

// async global->LDS, 16B per lane; LDS dest = wave-uniform base + lane*16
#define GLD_LDS(g, l) __builtin_amdgcn_global_load_lds( \
    (const __attribute__((address_space(1))) unsigned int*)(g), \
    (__attribute__((address_space(3))) unsigned int*)(l), 16, 0, 0)

#define MFMA_BF16_16x16x32 __builtin_amdgcn_mfma_f32_16x16x32_bf16

// ---------------- fused weight prep ----------------
__global__ __launch_bounds__(256) void prep(
    const float* __restrict__ wq, const float* __restrict__ wk,
    const float* __restrict__ wv, const float* __restrict__ w1,
    const float* __restrict__ w2, const float* __restrict__ bq,
    const float* __restrict__ bk,
    bf16_t* __restrict__ wqk_hi, bf16_t* __restrict__ wqk_lo,
    bf16_t* __restrict__ wvb, bf16_t* __restrict__ w1b, bf16_t* __restrict__ w2b,
    float* __restrict__ bqk) {
  const int blk = blockIdx.x, tid = threadIdx.x;
  if (blk < 2048) {                       // wq / wk split
    const int qk = blk >> 10;             // 0 = q, 1 = k
    const int i  = (blk & 1023) * 256 + tid;
    const float* src = qk ? wk : wq;
    float4 v = ((const float4*)src)[i];
    float f[4] = {v.x, v.y, v.z, v.w};
    bf16x4 h, l;
    #pragma unroll
    for (int j = 0; j < 4; ++j) { h[j] = (bf16_t)f[j]; l[j] = (bf16_t)(f[j] - (float)h[j]); }
    ((bf16x4*)(wqk_hi + qk * 1024 * 1024))[i] = h;
    ((bf16x4*)(wqk_lo + qk * 1024 * 1024))[i] = l;
  } else if (blk < 3072) {                // wv cast
    const int i = (blk - 2048) * 256 + tid;
    float4 v = ((const float4*)wv)[i];
    bf16x4 o; o[0]=(bf16_t)v.x; o[1]=(bf16_t)v.y; o[2]=(bf16_t)v.z; o[3]=(bf16_t)v.w;
    ((bf16x4*)wvb)[i] = o;
  } else if (blk < 7168) {                // w1 cast
    const int i = (blk - 3072) * 256 + tid;
    float4 v = ((const float4*)w1)[i];
    bf16x4 o; o[0]=(bf16_t)v.x; o[1]=(bf16_t)v.y; o[2]=(bf16_t)v.z; o[3]=(bf16_t)v.w;
    ((bf16x4*)w1b)[i] = o;
  } else if (blk < 11264) {               // w2 cast
    const int i = (blk - 7168) * 256 + tid;
    float4 v = ((const float4*)w2)[i];
    bf16x4 o; o[0]=(bf16_t)v.x; o[1]=(bf16_t)v.y; o[2]=(bf16_t)v.z; o[3]=(bf16_t)v.w;
    ((bf16x4*)w2b)[i] = o;
  } else {                                // bias concat
    const int i = (blk - 11264) * 256 + tid;
    if (i < 1024) { bqk[i] = bq[i]; bqk[1024 + i] = bk[i]; }
  }
}

// ---------------- LN helpers ----------------

__device__ __forceinline__ void block_sum2(float& s, float& ss, float* red) {
  #pragma unroll
  for (int off = 32; off > 0; off >>= 1) {
    s  += __shfl_down(s, off);
    ss += __shfl_down(ss, off);
  }
  const int wave = threadIdx.x >> 6;
  if ((threadIdx.x & 63) == 0) { red[wave * 2] = s; red[wave * 2 + 1] = ss; }
  __syncthreads();
  s  = red[0] + red[2] + red[4] + red[6];
  ss = red[1] + red[3] + red[5] + red[7];
}

// LN over D=1024, fp32 in -> hi/lo bf16 out.
__global__ __launch_bounds__(256) void ln_fwd_split(const float* __restrict__ x,
    const float* __restrict__ g, const float* __restrict__ b,
    bf16_t* __restrict__ out_hi, bf16_t* __restrict__ out_lo) {
  __shared__ float red[8];
  const size_t row = blockIdx.x;
  float4 v = ((const float4*)(x + row * 1024))[threadIdx.x];
  float s  = v.x + v.y + v.z + v.w;
  float ss = v.x*v.x + v.y*v.y + v.z*v.z + v.w*v.w;
  block_sum2(s, ss, red);
  const float mu  = s * (1.f / 1024.f);
  const float var = ss * (1.f / 1024.f) - mu * mu;
  const float rs  = rsqrtf(var + 1e-5f);
  float4 gg = ((const float4*)g)[threadIdx.x];
  float4 bb = ((const float4*)b)[threadIdx.x];
  float f[4];
  f[0] = (v.x - mu) * rs * gg.x + bb.x;
  f[1] = (v.y - mu) * rs * gg.y + bb.y;
  f[2] = (v.z - mu) * rs * gg.z + bb.z;
  f[3] = (v.w - mu) * rs * gg.w + bb.w;
  bf16x4 oh, ol;
  #pragma unroll
  for (int j = 0; j < 4; ++j) {
    oh[j] = (bf16_t)f[j];
    ol[j] = (bf16_t)(f[j] - (float)oh[j]);
  }
  ((bf16x4*)(out_hi + row * 1024))[threadIdx.x] = oh;
  ((bf16x4*)(out_lo + row * 1024))[threadIdx.x] = ol;
}

// t = x + attn; LN(t) -> bf16. (no second residual in reference)
__global__ __launch_bounds__(256) void resid_ln_fwd(const float* __restrict__ x,
    const float* __restrict__ a, const float* __restrict__ g, const float* __restrict__ b,
    bf16_t* __restrict__ out) {
  __shared__ float red[8];
  const size_t row = blockIdx.x;
  float4 v = ((const float4*)(x + row * 1024))[threadIdx.x];
  float4 av = ((const float4*)(a + row * 1024))[threadIdx.x];
  v.x += av.x; v.y += av.y; v.z += av.z; v.w += av.w;
  float s  = v.x + v.y + v.z + v.w;
  float ss = v.x*v.x + v.y*v.y + v.z*v.z + v.w*v.w;
  block_sum2(s, ss, red);
  const float mu  = s * (1.f / 1024.f);
  const float var = ss * (1.f / 1024.f) - mu * mu;
  const float rs  = rsqrtf(var + 1e-5f);
  float4 gg = ((const float4*)g)[threadIdx.x];
  float4 bb = ((const float4*)b)[threadIdx.x];
  bf16x4 o;
  o[0] = (bf16_t)((v.x - mu) * rs * gg.x + bb.x);
  o[1] = (bf16_t)((v.y - mu) * rs * gg.y + bb.y);
  o[2] = (bf16_t)((v.z - mu) * rs * gg.z + bb.z);
  o[3] = (bf16_t)((v.w - mu) * rs * gg.w + bb.w);
  ((bf16x4*)(out + row * 1024))[threadIdx.x] = o;
}

// LN over F=4096 + ReLU, bf16 in-place. 16 elems/thread.
__global__ __launch_bounds__(256) void ln_relu_inplace(bf16_t* __restrict__ m,
    const float* __restrict__ g, const float* __restrict__ b) {
  __shared__ float red[8];
  const size_t row = blockIdx.x;
  bf16_t* mr = m + row * 4096;
  const int base = threadIdx.x * 16;
  bf16x8 v0 = *(bf16x8*)(mr + base);
  bf16x8 v1 = *(bf16x8*)(mr + base + 8);
  float f[16];
  #pragma unroll
  for (int i = 0; i < 8; ++i) { f[i] = (float)v0[i]; f[8 + i] = (float)v1[i]; }
  float s = 0.f, ss = 0.f;
  #pragma unroll
  for (int i = 0; i < 16; ++i) { s += f[i]; ss += f[i] * f[i]; }
  block_sum2(s, ss, red);
  const float mu  = s * (1.f / 4096.f);
  const float var = ss * (1.f / 4096.f) - mu * mu;
  const float rs  = rsqrtf(var + 1e-5f);
  bf16x8 o0, o1;
  #pragma unroll
  for (int i = 0; i < 16; ++i) {
    float ov = (f[i] - mu) * rs * g[base + i] + b[base + i];
    ov = fmaxf(ov, 0.f);
    if (i < 8) o0[i] = (bf16_t)ov; else o1[i - 8] = (bf16_t)ov;
  }
  *(bf16x8*)(mr + base) = o0;
  *(bf16x8*)(mr + base + 8) = o1;
}

// ---------------- GEMM: C[M,N] = A[M,K] * B[N,K]^T + bias ----------------
// OUT_MODE: 0 = fp32 row-major, 1 = bf16 row-major, 2 = bf16 head-major [b,h,n,64]
template <int OUT_MODE>
__global__ __launch_bounds__(256) void gemm_bt(
    const bf16_t* __restrict__ A, const bf16_t* __restrict__ Bw,
    const float* __restrict__ bias, void* __restrict__ Cp,
    int M, int N, int K) {
  __shared__ bf16_t As[128 * 32];
  __shared__ bf16_t Bs[128 * 32];
  const int tid  = threadIdx.x;
  const int wave = tid >> 6, lane = tid & 63;
  const int quad = lane >> 4, l15 = lane & 15;
  const int m0 = blockIdx.x * 128, n0 = blockIdx.y * 128;
  const int wm = (wave >> 1) * 64, wn = (wave & 1) * 64;
  const int srow = wave * 32 + (lane >> 2);
  const int scol = (lane & 3) * 8;

  floatx4 acc[4][4] = {};

  const bf16_t* Ag = A  + (size_t)(m0 + srow) * K + scol;
  const bf16_t* Bg = Bw + (size_t)(n0 + srow) * K + scol;

  for (int k0 = 0; k0 < K; k0 += 32) {
    __syncthreads();
    #pragma unroll
    for (int i = 0; i < 2; ++i) {
      GLD_LDS(Ag + (size_t)(i * 16) * K + k0, As + wave * 1024 + i * 512);
      GLD_LDS(Bg + (size_t)(i * 16) * K + k0, Bs + wave * 1024 + i * 512);
    }
    __syncthreads();
    bf16x8 af[4], bfr[4];
    #pragma unroll
    for (int i = 0; i < 4; ++i)
      af[i] = *(const bf16x8*)(As + (wm + i * 16 + l15) * 32 + quad * 8);
    #pragma unroll
    for (int j = 0; j < 4; ++j)
      bfr[j] = *(const bf16x8*)(Bs + (wn + j * 16 + l15) * 32 + quad * 8);
    #pragma unroll
    for (int i = 0; i < 4; ++i)
      #pragma unroll
      for (int j = 0; j < 4; ++j)
        acc[i][j] = MFMA_BF16_16x16x32(af[i], bfr[j], acc[i][j], 0, 0, 0);
  }
  #pragma unroll
  for (int j = 0; j < 4; ++j) {
    const int col = n0 + wn + j * 16 + l15;
    const float bv = bias[col];
    #pragma unroll
    for (int i = 0; i < 4; ++i) {
      #pragma unroll
      for (int r = 0; r < 4; ++r) {
        const int row = m0 + wm + i * 16 + quad * 4 + r;
        const float v = acc[i][j][r] + bv;
        if (OUT_MODE == 0) {
          ((float*)Cp)[(size_t)row * N + col] = v;
        } else if (OUT_MODE == 1) {
          ((bf16_t*)Cp)[(size_t)row * N + col] = (bf16_t)v;
        } else {
          const int b = row >> 11, n = row & 2047;
          const int h = col >> 6, e = col & 63;
          ((bf16_t*)Cp)[(((size_t)((b << 4) + h) * 2048 + n) << 6) + e] = (bf16_t)v;
        }
      }
    }
  }
}

// K-split GEMM for MLP2 (grid.z selects K-half; fp32 partials, no bias).
__global__ __launch_bounds__(256) void gemm_bt_ksplit(
    const bf16_t* __restrict__ A, const bf16_t* __restrict__ Bw,
    float* __restrict__ C0, float* __restrict__ C1,
    int M, int N, int K, int Kh) {
  __shared__ bf16_t As[128 * 32];
  __shared__ bf16_t Bs[128 * 32];
  const int tid  = threadIdx.x;
  const int wave = tid >> 6, lane = tid & 63;
  const int quad = lane >> 4, l15 = lane & 15;
  const int m0 = blockIdx.x * 128, n0 = blockIdx.y * 128;
  const int wm = (wave >> 1) * 64, wn = (wave & 1) * 64;
  const int srow = wave * 32 + (lane >> 2);
  const int scol = (lane & 3) * 8;

  floatx4 acc[4][4] = {};

  const bf16_t* Ag = A  + (size_t)(m0 + srow) * K + scol;
  const bf16_t* Bg = Bw + (size_t)(n0 + srow) * K + scol;

  const int kbeg = blockIdx.z * Kh, kend = kbeg + Kh;
  for (int k0 = kbeg; k0 < kend; k0 += 32) {
    __syncthreads();
    #pragma unroll
    for (int i = 0; i < 2; ++i) {
      GLD_LDS(Ag + (size_t)(i * 16) * K + k0, As + wave * 1024 + i * 512);
      GLD_LDS(Bg + (size_t)(i * 16) * K + k0, Bs + wave * 1024 + i * 512);
    }
    __syncthreads();
    bf16x8 af[4], bfr[4];
    #pragma unroll
    for (int i = 0; i < 4; ++i)
      af[i] = *(const bf16x8*)(As + (wm + i * 16 + l15) * 32 + quad * 8);
    #pragma unroll
    for (int j = 0; j < 4; ++j)
      bfr[j] = *(const bf16x8*)(Bs + (wn + j * 16 + l15) * 32 + quad * 8);
    #pragma unroll
    for (int i = 0; i < 4; ++i)
      #pragma unroll
      for (int j = 0; j < 4; ++j)
        acc[i][j] = MFMA_BF16_16x16x32(af[i], bfr[j], acc[i][j], 0, 0, 0);
  }
  float* Cp = blockIdx.z ? C1 : C0;
  #pragma unroll
  for (int j = 0; j < 4; ++j) {
    const int col = n0 + wn + j * 16 + l15;
    #pragma unroll
    for (int i = 0; i < 4; ++i) {
      #pragma unroll
      for (int r = 0; r < 4; ++r) {
        const int row = m0 + wm + i * 16 + quad * 4 + r;
        Cp[(size_t)row * N + col] = acc[i][j][r];
      }
    }
  }
}

// out = a + b + bias  (fp32, row-major [4096,1024])
__global__ __launch_bounds__(256) void add2_bias(
    const float* __restrict__ a, const float* __restrict__ b,
    const float* __restrict__ bias, float* __restrict__ out) {
  const size_t row = blockIdx.x;
  const int c = threadIdx.x * 4;
  float4 va = *(const float4*)(a + row * 1024 + c);
  float4 vb = *(const float4*)(b + row * 1024 + c);
  float4 vc = *(const float4*)(bias + c);
  float4 o4;
  o4.x = va.x + vb.x + vc.x;
  o4.y = va.y + vb.y + vc.y;
  o4.z = va.z + vb.z + vc.z;
  o4.w = va.w + vb.w + vc.w;
  *(float4*)(out + row * 1024 + c) = o4;
}

// Split-precision GEMM for q,k: 3-term bf16 emulation of fp32.
// Writes q (cols<1024, scaled by 32=sqrt(D)) and k head-major, split hi/lo.
__global__ __launch_bounds__(256) void gemm_qk_split(
    const bf16_t* __restrict__ Ah, const bf16_t* __restrict__ Al,
    const bf16_t* __restrict__ Bh, const bf16_t* __restrict__ Bl,
    const float* __restrict__ bias,
    bf16_t* __restrict__ qhi, bf16_t* __restrict__ qlo,
    bf16_t* __restrict__ khi, bf16_t* __restrict__ klo,
    int M, int N, int K) {
  __shared__ bf16_t Ash[128 * 32];
  __shared__ bf16_t Asl[128 * 32];
  __shared__ bf16_t Bsh[128 * 32];
  __shared__ bf16_t Bsl[128 * 32];
  const int tid  = threadIdx.x;
  const int wave = tid >> 6, lane = tid & 63;
  const int quad = lane >> 4, l15 = lane & 15;
  const int m0 = blockIdx.x * 128, n0 = blockIdx.y * 128;
  const int wm = (wave >> 1) * 64, wn = (wave & 1) * 64;
  const int srow = wave * 32 + (lane >> 2);
  const int scol = (lane & 3) * 8;

  floatx4 acc[4][4] = {};

  const size_t aoff = (size_t)(m0 + srow) * K + scol;
  const size_t boff = (size_t)(n0 + srow) * K + scol;

  for (int k0 = 0; k0 < K; k0 += 32) {
    __syncthreads();
    #pragma unroll
    for (int i = 0; i < 2; ++i) {
      const size_t ga = aoff + (size_t)(i * 16) * K + k0;
      const size_t gb = boff + (size_t)(i * 16) * K + k0;
      GLD_LDS(Ah + ga, Ash + wave * 1024 + i * 512);
      GLD_LDS(Al + ga, Asl + wave * 1024 + i * 512);
      GLD_LDS(Bh + gb, Bsh + wave * 1024 + i * 512);
      GLD_LDS(Bl + gb, Bsl + wave * 1024 + i * 512);
    }
    __syncthreads();
    bf16x8 ah[4], al[4], bh[4], bl[4];
    #pragma unroll
    for (int i = 0; i < 4; ++i) {
      const int ro = (wm + i * 16 + l15) * 32 + quad * 8;
      ah[i] = *(const bf16x8*)(Ash + ro);
      al[i] = *(const bf16x8*)(Asl + ro);
    }
    #pragma unroll
    for (int j = 0; j < 4; ++j) {
      const int ro = (wn + j * 16 + l15) * 32 + quad * 8;
      bh[j] = *(const bf16x8*)(Bsh + ro);
      bl[j] = *(const bf16x8*)(Bsl + ro);
    }
    #pragma unroll
    for (int i = 0; i < 4; ++i)
      #pragma unroll
      for (int j = 0; j < 4; ++j) {
        acc[i][j] = MFMA_BF16_16x16x32(ah[i], bh[j], acc[i][j], 0, 0, 0);
        acc[i][j] = MFMA_BF16_16x16x32(ah[i], bl[j], acc[i][j], 0, 0, 0);
        acc[i][j] = MFMA_BF16_16x16x32(al[i], bh[j], acc[i][j], 0, 0, 0);
      }
  }
  #pragma unroll
  for (int j = 0; j < 4; ++j) {
    const int col = n0 + wn + j * 16 + l15;       // [0,2048)
    const float bv = bias[col];
    const bool isq = col < 1024;
    bf16_t* hib = isq ? qhi : khi;
    bf16_t* lob = isq ? qlo : klo;
    const float scale = isq ? 32.0f : 1.0f;       // sqrt(D) folded into q
    const int h = (col >> 6) & 15, e = col & 63;
    #pragma unroll
    for (int i = 0; i < 4; ++i) {
      #pragma unroll
      for (int r = 0; r < 4; ++r) {
        const int row = m0 + wm + i * 16 + quad * 4 + r;
        const int b = row >> 11, n = row & 2047;
        const float c = (acc[i][j][r] + bv) * scale;
        const bf16_t chi = (bf16_t)c;
        const bf16_t clo = (bf16_t)(c - (float)chi);
        const size_t dst = (((size_t)((b << 4) + h) * 2048 + n) << 6) + e;
        hib[dst] = chi;
        lob[dst] = clo;
      }
    }
  }
}

// ---------------- V transpose: [bh][n][64] -> [bh][e][2048] ----------------
__global__ __launch_bounds__(256) void transpose_v(
    const bf16_t* __restrict__ vhm, bf16_t* __restrict__ vT) {
  __shared__ bf16_t T[64 * 72];
  const int bh = blockIdx.x, n0 = blockIdx.y * 64;
  const int r = threadIdx.x >> 2;          // 0..63
  const int c = (threadIdx.x & 3) * 16;    // 0,16,32,48
  const bf16_t* src = vhm + ((size_t)bh * 2048 + n0 + r) * 64 + c;
  bf16x8 a0 = *(const bf16x8*)src;
  bf16x8 a1 = *(const bf16x8*)(src + 8);
  #pragma unroll
  for (int j = 0; j < 8; ++j) {
    T[(c + j) * 72 + r]     = a0[j];
    T[(c + 8 + j) * 72 + r] = a1[j];
  }
  __syncthreads();
  bf16x8 o0 = *(const bf16x8*)(T + r * 72 + c);
  bf16x8 o1 = *(const bf16x8*)(T + r * 72 + c + 8);
  bf16_t* dst = vT + ((size_t)(bh * 64 + r)) * 2048 + n0 + c;
  *(bf16x8*)dst = o0;
  *(bf16x8*)(dst + 8) = o1;
}

// ---------------- barrier-free causal flash attention ----------------
// 4 independent waves/block (no __syncthreads); wave owns 16 q-rows; TK=64.
// K/V consumed directly from global as MFMA B-fragments (L2 serves reuse;
// grid x=q-tile, y=head so co-resident blocks share one head's K/V).
// Row max via 4x shfl; row sum via ones-MFMA (consumes the same bf16 P from
// LDS -> denominator exactly matches numerator). NO launch_bounds cap:
// natural VGPR ~110 -> 4 waves/SIMD without spill (R9's forced 64 spilled).
__global__ __launch_bounds__(256) void attn_causal(
    const bf16_t* __restrict__ qhi, const bf16_t* __restrict__ qlo,
    const bf16_t* __restrict__ khi, const bf16_t* __restrict__ klo,
    const bf16_t* __restrict__ vT, float* __restrict__ o) {
  __shared__ bf16_t Ps[4][16 * 72];   // per-wave P: 16 rows x 64 cols, stride 72

  const int tid  = threadIdx.x;
  const int wave = tid >> 6, lane = tid & 63;
  const int quad = lane >> 4, l15 = lane & 15;
  const int q0 = (31 - (int)blockIdx.x) * 64;   // heavy q-tiles dispatch first
  const int bh = blockIdx.y;                    // same-head blocks adjacent
  const size_t hb = (size_t)bh * 2048;
  const int wmin = q0 + wave * 16;              // wave's 16 rows

  // Q fragments (A-layout: m=l15, k=quad*8+j)
  const bf16_t* qbh = qhi + ((hb + wmin + l15) << 6) + quad * 8;
  const bf16_t* qbl = qlo + ((hb + wmin + l15) << 6) + quad * 8;
  const bf16x8 qh0 = *(const bf16x8*)qbh, qh1 = *(const bf16x8*)(qbh + 32);
  const bf16x8 ql0 = *(const bf16x8*)qbl, ql1 = *(const bf16x8*)(qbl + 32);

  bf16x8 ones;
  #pragma unroll
  for (int j = 0; j < 8; ++j) ones[j] = (bf16_t)1.0f;

  floatx4 accO[4] = {};
  floatx4 accL = {};                            // row-sum accumulator
  float m_row[4] = {-1e30f, -1e30f, -1e30f, -1e30f};

  const int ntiles = (q0 >> 6) + 1;
  for (int t = 0; t < ntiles; ++t) {
    const int k0 = t * 64;
    const bool needmask = (k0 + 63 > wmin);

    // S = Q K^T; K B-frags straight from global (coalesced 16B/lane)
    floatx4 sv[4];
    #pragma unroll
    for (int jj = 0; jj < 4; ++jj) {
      const bf16_t* kbh = khi + ((hb + k0 + jj * 16 + l15) << 6) + quad * 8;
      const bf16_t* kbl = klo + ((hb + k0 + jj * 16 + l15) << 6) + quad * 8;
      const bf16x8 kh0 = *(const bf16x8*)kbh;
      const bf16x8 kh1 = *(const bf16x8*)(kbh + 32);
      const bf16x8 kl0 = *(const bf16x8*)kbl;
      const bf16x8 kl1 = *(const bf16x8*)(kbl + 32);
      floatx4 a = {};
      a = MFMA_BF16_16x16x32(qh0, kh0, a, 0, 0, 0);
      a = MFMA_BF16_16x16x32(qh1, kh1, a, 0, 0, 0);
      a = MFMA_BF16_16x16x32(qh0, kl0, a, 0, 0, 0);
      a = MFMA_BF16_16x16x32(qh1, kl1, a, 0, 0, 0);
      a = MFMA_BF16_16x16x32(ql0, kh0, a, 0, 0, 0);
      a = MFMA_BF16_16x16x32(ql1, kh1, a, 0, 0, 0);
      sv[jj] = a;
    }

    // online softmax; lane owns rows quad*4+r, cols jj*16+l15
    const int colb = k0 + l15;
    #pragma unroll
    for (int r = 0; r < 4; ++r) {
      const int rowg = wmin + quad * 4 + r;
      float sr[4], mr = -1e30f;
      #pragma unroll
      for (int jj = 0; jj < 4; ++jj) {
        float x = sv[jj][r];
        if (needmask && (colb + jj * 16 > rowg)) x = -1e30f;   // causal mask
        sr[jj] = x;
        mr = fmaxf(mr, x);
      }
      mr = fmaxf(mr, __shfl_xor(mr, 1));
      mr = fmaxf(mr, __shfl_xor(mr, 2));
      mr = fmaxf(mr, __shfl_xor(mr, 4));
      mr = fmaxf(mr, __shfl_xor(mr, 8));
      const float mnew = fmaxf(m_row[r], mr);
      const float alpha = __expf(m_row[r] - mnew);
      m_row[r] = mnew;
      #pragma unroll
      for (int jj = 0; jj < 4; ++jj)
        Ps[wave][(quad * 4 + r) * 72 + jj * 16 + l15] = (bf16_t)__expf(sr[jj] - mnew);
      #pragma unroll
      for (int j = 0; j < 4; ++j) accO[j][r] *= alpha;
      accL[r] *= alpha;
    }
    // Ps is wave-private: LDS completion is enough (no barrier in kernel)
    asm volatile("s_waitcnt lgkmcnt(0)" ::: "memory");

    // P A-frags (2 k-chunks of 32 keys)
    const bf16x8 pf0 = *(const bf16x8*)(&Ps[wave][l15 * 72 + quad * 8]);
    const bf16x8 pf1 = *(const bf16x8*)(&Ps[wave][l15 * 72 + 32 + quad * 8]);

    // row-sum via ones-MFMA (exactly matches bf16 P numerator)
    accL = MFMA_BF16_16x16x32(pf0, ones, accL, 0, 0, 0);
    accL = MFMA_BF16_16x16x32(pf1, ones, accL, 0, 0, 0);

    // O += P V  (V B-frags straight from vT global)
    #pragma unroll
    for (int j = 0; j < 4; ++j) {
      const bf16_t* vrow = vT + ((size_t)(bh * 64 + j * 16 + l15)) * 2048 + k0 + quad * 8;
      const bf16x8 vf0 = *(const bf16x8*)vrow;
      const bf16x8 vf1 = *(const bf16x8*)(vrow + 32);
      accO[j] = MFMA_BF16_16x16x32(pf0, vf0, accO[j], 0, 0, 0);
      accO[j] = MFMA_BF16_16x16x32(pf1, vf1, accO[j], 0, 0, 0);
    }
  }

  // normalize + write (token-major fp32 for resid_ln); accL[r] = l on all lanes
  const int b = bh >> 4, h = bh & 15;
  #pragma unroll
  for (int r = 0; r < 4; ++r) {
    const float linv = 1.f / accL[r];
    const int qr = wmin + quad * 4 + r;
    float* orow = o + ((size_t)(b * 2048) + qr) * 1024 + h * 64;
    #pragma unroll
    for (int j = 0; j < 4; ++j)
      orow[j * 16 + l15] = accO[j][r] * linv;
  }
}

// ---------------- launcher ----------------

extern "C" void kernel_launch(void* const* d_in, const int* in_sizes, int n_in,
                              void* d_out, int out_size, void* d_ws, size_t ws_size,
                              hipStream_t stream) {
  const float* x        = (const float*)d_in[0];
  const float* wq       = (const float*)d_in[1];
  const float* bq       = (const float*)d_in[2];
  const float* wk       = (const float*)d_in[3];
  const float* bk       = (const float*)d_in[4];
  const float* wv       = (const float*)d_in[5];
  const float* bv       = (const float*)d_in[6];
  const float* w1       = (const float*)d_in[7];
  const float* b1       = (const float*)d_in[8];
  const float* ln_mlp_g = (const float*)d_in[9];
  const float* ln_mlp_b = (const float*)d_in[10];
  const float* w2       = (const float*)d_in[11];
  const float* b2       = (const float*)d_in[12];
  const float* ln1_g    = (const float*)d_in[13];
  const float* ln1_b    = (const float*)d_in[14];
  const float* ln2_g    = (const float*)d_in[15];
  const float* ln2_b    = (const float*)d_in[16];

  // workspace layout (MiB offsets), aliased by phase lifetime:
  char* ws = (char*)d_ws;
  bf16_t* w1b    = (bf16_t*)(ws);                  // [0,8)
  bf16_t* w2b    = (bf16_t*)(ws + (8u   << 20));   // [8,16)
  bf16_t* qhi    = (bf16_t*)(ws + (16u  << 20));   // [16,24)
  bf16_t* qlo    = (bf16_t*)(ws + (24u  << 20));   // [24,32)
  bf16_t* khi    = (bf16_t*)(ws + (32u  << 20));   // [32,40)
  bf16_t* klo    = (bf16_t*)(ws + (40u  << 20));   // [40,48)
  bf16_t* mbuf   = (bf16_t*)(ws + (16u  << 20));   // [16,48)  (aliases q/k, dead by MLP1)
  bf16_t* wqk_hi = (bf16_t*)(ws + (48u  << 20));   // [48,52)
  bf16_t* wqk_lo = (bf16_t*)(ws + (52u  << 20));   // [52,56)
  bf16_t* vhm    = (bf16_t*)(ws + (48u  << 20));   // [48,56)  (aliases wqk, dead after qk gemm)
  bf16_t* wvb    = (bf16_t*)(ws + (56u  << 20));   // [56,58)
  float*  bqk    = (float*) (ws + (58u  << 20));   // [58,~)
  float*  attnb  = (float*) (ws + (48u  << 20));   // [48,64)  (aliases vhm/wvb/bqk, dead by attn)
  float*  part0  = (float*) (ws + (48u  << 20));   // [48,64)  (attnb dead by MLP2)
  bf16_t* h_hi   = (bf16_t*)(ws + (60u  << 20));   // [60,68)
  bf16_t* h_lo   = (bf16_t*)(ws + (68u  << 20));   // [68,76)
  bf16_t* h2     = (bf16_t*)(ws + (64u  << 20));   // [64,72)  (aliases h_lo, dead by resid_ln)
  bf16_t* vTb    = (bf16_t*)(ws + (76u  << 20));   // [76,84)
  float*  part1  = (float*) (ws + (84u  << 20));   // [84,100) (vTb dead by MLP2)

  prep<<<11268, 256, 0, stream>>>(wq, wk, wv, w1, w2, bq, bk,
                                  wqk_hi, wqk_lo, wvb, w1b, w2b, bqk);

  ln_fwd_split<<<4096, 256, 0, stream>>>(x, ln1_g, ln1_b, h_hi, h_lo);
  gemm_qk_split<<<dim3(32, 16), 256, 0, stream>>>(h_hi, h_lo, wqk_hi, wqk_lo, bqk,
                                                  qhi, qlo, khi, klo, 4096, 2048, 1024);
  gemm_bt<2><<<dim3(32, 8), 256, 0, stream>>>(h_hi, wvb, bv, vhm, 4096, 1024, 1024);
  transpose_v<<<dim3(32, 32), 256, 0, stream>>>(vhm, vTb);
  attn_causal<<<dim3(32, 32), 256, 0, stream>>>(qhi, qlo, khi, klo, vTb, attnb);
  resid_ln_fwd<<<4096, 256, 0, stream>>>(x, attnb, ln2_g, ln2_b, h2);
  gemm_bt<1><<<dim3(32, 32), 256, 0, stream>>>(h2, w1b, b1, mbuf, 4096, 4096, 1024);
  ln_relu_inplace<<<4096, 256, 0, stream>>>(mbuf, ln_mlp_g, ln_mlp_b);
  gemm_bt_ksplit<<<dim3(32, 8, 2), 256, 0, stream>>>(mbuf, w2b, part0, part1,
                                                     4096, 1024, 4096, 2048);
  add2_bias<<<4096, 256, 0, stream>>>(part0, part1, b2, (float*)d_out);

  (void)in_sizes; (void)n_in; (void)out_size; (void)ws_size;
}

// Round 11
// 577.792 us; speedup vs baseline: 1.2073x; 1.2073x over previous
//
#include <hip/hip_runtime.h>
#include <cstdint>

typedef __bf16 bf16_t;
typedef bf16_t bf16x8 __attribute__((ext_vector_type(8)));
typedef bf16_t bf16x4 __attribute__((ext_vector_type(4)));
typedef float  floatx4 __attribute__((ext_vector_type(4)));

// async global->LDS, 16B per lane; LDS dest = wave-uniform base + lane*16
#define GLD_LDS(g, l) __builtin_amdgcn_global_load_lds( \
    (const __attribute__((address_space(1))) unsigned int*)(g), \
    (__attribute__((address_space(3))) unsigned int*)(l), 16, 0, 0)

#define MFMA_BF16_16x16x32 __builtin_amdgcn_mfma_f32_16x16x32_bf16

// ---------------- fused weight prep ----------------
__global__ __launch_bounds__(256) void prep(
    const float* __restrict__ wq, const float* __restrict__ wk,
    const float* __restrict__ wv, const float* __restrict__ w1,
    const float* __restrict__ w2, const float* __restrict__ bq,
    const float* __restrict__ bk,
    bf16_t* __restrict__ wqk_hi, bf16_t* __restrict__ wqk_lo,
    bf16_t* __restrict__ wvb, bf16_t* __restrict__ w1b, bf16_t* __restrict__ w2b,
    float* __restrict__ bqk) {
  const int blk = blockIdx.x, tid = threadIdx.x;
  if (blk < 2048) {                       // wq / wk split
    const int qk = blk >> 10;             // 0 = q, 1 = k
    const int i  = (blk & 1023) * 256 + tid;
    const float* src = qk ? wk : wq;
    float4 v = ((const float4*)src)[i];
    float f[4] = {v.x, v.y, v.z, v.w};
    bf16x4 h, l;
    #pragma unroll
    for (int j = 0; j < 4; ++j) { h[j] = (bf16_t)f[j]; l[j] = (bf16_t)(f[j] - (float)h[j]); }
    ((bf16x4*)(wqk_hi + qk * 1024 * 1024))[i] = h;
    ((bf16x4*)(wqk_lo + qk * 1024 * 1024))[i] = l;
  } else if (blk < 3072) {                // wv cast
    const int i = (blk - 2048) * 256 + tid;
    float4 v = ((const float4*)wv)[i];
    bf16x4 o; o[0]=(bf16_t)v.x; o[1]=(bf16_t)v.y; o[2]=(bf16_t)v.z; o[3]=(bf16_t)v.w;
    ((bf16x4*)wvb)[i] = o;
  } else if (blk < 7168) {                // w1 cast
    const int i = (blk - 3072) * 256 + tid;
    float4 v = ((const float4*)w1)[i];
    bf16x4 o; o[0]=(bf16_t)v.x; o[1]=(bf16_t)v.y; o[2]=(bf16_t)v.z; o[3]=(bf16_t)v.w;
    ((bf16x4*)w1b)[i] = o;
  } else if (blk < 11264) {               // w2 cast
    const int i = (blk - 7168) * 256 + tid;
    float4 v = ((const float4*)w2)[i];
    bf16x4 o; o[0]=(bf16_t)v.x; o[1]=(bf16_t)v.y; o[2]=(bf16_t)v.z; o[3]=(bf16_t)v.w;
    ((bf16x4*)w2b)[i] = o;
  } else {                                // bias concat
    const int i = (blk - 11264) * 256 + tid;
    if (i < 1024) { bqk[i] = bq[i]; bqk[1024 + i] = bk[i]; }
  }
}

// ---------------- LN helpers ----------------

__device__ __forceinline__ void block_sum2(float& s, float& ss, float* red) {
  #pragma unroll
  for (int off = 32; off > 0; off >>= 1) {
    s  += __shfl_down(s, off);
    ss += __shfl_down(ss, off);
  }
  const int wave = threadIdx.x >> 6;
  if ((threadIdx.x & 63) == 0) { red[wave * 2] = s; red[wave * 2 + 1] = ss; }
  __syncthreads();
  s  = red[0] + red[2] + red[4] + red[6];
  ss = red[1] + red[3] + red[5] + red[7];
}

// LN over D=1024, fp32 in -> hi/lo bf16 out.
__global__ __launch_bounds__(256) void ln_fwd_split(const float* __restrict__ x,
    const float* __restrict__ g, const float* __restrict__ b,
    bf16_t* __restrict__ out_hi, bf16_t* __restrict__ out_lo) {
  __shared__ float red[8];
  const size_t row = blockIdx.x;
  float4 v = ((const float4*)(x + row * 1024))[threadIdx.x];
  float s  = v.x + v.y + v.z + v.w;
  float ss = v.x*v.x + v.y*v.y + v.z*v.z + v.w*v.w;
  block_sum2(s, ss, red);
  const float mu  = s * (1.f / 1024.f);
  const float var = ss * (1.f / 1024.f) - mu * mu;
  const float rs  = rsqrtf(var + 1e-5f);
  float4 gg = ((const float4*)g)[threadIdx.x];
  float4 bb = ((const float4*)b)[threadIdx.x];
  float f[4];
  f[0] = (v.x - mu) * rs * gg.x + bb.x;
  f[1] = (v.y - mu) * rs * gg.y + bb.y;
  f[2] = (v.z - mu) * rs * gg.z + bb.z;
  f[3] = (v.w - mu) * rs * gg.w + bb.w;
  bf16x4 oh, ol;
  #pragma unroll
  for (int j = 0; j < 4; ++j) {
    oh[j] = (bf16_t)f[j];
    ol[j] = (bf16_t)(f[j] - (float)oh[j]);
  }
  ((bf16x4*)(out_hi + row * 1024))[threadIdx.x] = oh;
  ((bf16x4*)(out_lo + row * 1024))[threadIdx.x] = ol;
}

// t = x + attn; LN(t) -> bf16. (no second residual in reference)
__global__ __launch_bounds__(256) void resid_ln_fwd(const float* __restrict__ x,
    const float* __restrict__ a, const float* __restrict__ g, const float* __restrict__ b,
    bf16_t* __restrict__ out) {
  __shared__ float red[8];
  const size_t row = blockIdx.x;
  float4 v = ((const float4*)(x + row * 1024))[threadIdx.x];
  float4 av = ((const float4*)(a + row * 1024))[threadIdx.x];
  v.x += av.x; v.y += av.y; v.z += av.z; v.w += av.w;
  float s  = v.x + v.y + v.z + v.w;
  float ss = v.x*v.x + v.y*v.y + v.z*v.z + v.w*v.w;
  block_sum2(s, ss, red);
  const float mu  = s * (1.f / 1024.f);
  const float var = ss * (1.f / 1024.f) - mu * mu;
  const float rs  = rsqrtf(var + 1e-5f);
  float4 gg = ((const float4*)g)[threadIdx.x];
  float4 bb = ((const float4*)b)[threadIdx.x];
  bf16x4 o;
  o[0] = (bf16_t)((v.x - mu) * rs * gg.x + bb.x);
  o[1] = (bf16_t)((v.y - mu) * rs * gg.y + bb.y);
  o[2] = (bf16_t)((v.z - mu) * rs * gg.z + bb.z);
  o[3] = (bf16_t)((v.w - mu) * rs * gg.w + bb.w);
  ((bf16x4*)(out + row * 1024))[threadIdx.x] = o;
}

// LN over F=4096 + ReLU, bf16 in-place. 16 elems/thread.
__global__ __launch_bounds__(256) void ln_relu_inplace(bf16_t* __restrict__ m,
    const float* __restrict__ g, const float* __restrict__ b) {
  __shared__ float red[8];
  const size_t row = blockIdx.x;
  bf16_t* mr = m + row * 4096;
  const int base = threadIdx.x * 16;
  bf16x8 v0 = *(bf16x8*)(mr + base);
  bf16x8 v1 = *(bf16x8*)(mr + base + 8);
  float f[16];
  #pragma unroll
  for (int i = 0; i < 8; ++i) { f[i] = (float)v0[i]; f[8 + i] = (float)v1[i]; }
  float s = 0.f, ss = 0.f;
  #pragma unroll
  for (int i = 0; i < 16; ++i) { s += f[i]; ss += f[i] * f[i]; }
  block_sum2(s, ss, red);
  const float mu  = s * (1.f / 4096.f);
  const float var = ss * (1.f / 4096.f) - mu * mu;
  const float rs  = rsqrtf(var + 1e-5f);
  bf16x8 o0, o1;
  #pragma unroll
  for (int i = 0; i < 16; ++i) {
    float ov = (f[i] - mu) * rs * g[base + i] + b[base + i];
    ov = fmaxf(ov, 0.f);
    if (i < 8) o0[i] = (bf16_t)ov; else o1[i - 8] = (bf16_t)ov;
  }
  *(bf16x8*)(mr + base) = o0;
  *(bf16x8*)(mr + base + 8) = o1;
}

// ---------------- GEMM: C[M,N] = A[M,K] * B[N,K]^T + bias ----------------
// OUT_MODE: 0 = fp32 row-major, 1 = bf16 row-major, 2 = bf16 head-major [b,h,n,64]
template <int OUT_MODE>
__global__ __launch_bounds__(256) void gemm_bt(
    const bf16_t* __restrict__ A, const bf16_t* __restrict__ Bw,
    const float* __restrict__ bias, void* __restrict__ Cp,
    int M, int N, int K) {
  __shared__ bf16_t As[128 * 32];
  __shared__ bf16_t Bs[128 * 32];
  const int tid  = threadIdx.x;
  const int wave = tid >> 6, lane = tid & 63;
  const int quad = lane >> 4, l15 = lane & 15;
  const int m0 = blockIdx.x * 128, n0 = blockIdx.y * 128;
  const int wm = (wave >> 1) * 64, wn = (wave & 1) * 64;
  const int srow = wave * 32 + (lane >> 2);
  const int scol = (lane & 3) * 8;

  floatx4 acc[4][4] = {};

  const bf16_t* Ag = A  + (size_t)(m0 + srow) * K + scol;
  const bf16_t* Bg = Bw + (size_t)(n0 + srow) * K + scol;

  for (int k0 = 0; k0 < K; k0 += 32) {
    __syncthreads();
    #pragma unroll
    for (int i = 0; i < 2; ++i) {
      GLD_LDS(Ag + (size_t)(i * 16) * K + k0, As + wave * 1024 + i * 512);
      GLD_LDS(Bg + (size_t)(i * 16) * K + k0, Bs + wave * 1024 + i * 512);
    }
    __syncthreads();
    bf16x8 af[4], bfr[4];
    #pragma unroll
    for (int i = 0; i < 4; ++i)
      af[i] = *(const bf16x8*)(As + (wm + i * 16 + l15) * 32 + quad * 8);
    #pragma unroll
    for (int j = 0; j < 4; ++j)
      bfr[j] = *(const bf16x8*)(Bs + (wn + j * 16 + l15) * 32 + quad * 8);
    #pragma unroll
    for (int i = 0; i < 4; ++i)
      #pragma unroll
      for (int j = 0; j < 4; ++j)
        acc[i][j] = MFMA_BF16_16x16x32(af[i], bfr[j], acc[i][j], 0, 0, 0);
  }
  #pragma unroll
  for (int j = 0; j < 4; ++j) {
    const int col = n0 + wn + j * 16 + l15;
    const float bv = bias[col];
    #pragma unroll
    for (int i = 0; i < 4; ++i) {
      #pragma unroll
      for (int r = 0; r < 4; ++r) {
        const int row = m0 + wm + i * 16 + quad * 4 + r;
        const float v = acc[i][j][r] + bv;
        if (OUT_MODE == 0) {
          ((float*)Cp)[(size_t)row * N + col] = v;
        } else if (OUT_MODE == 1) {
          ((bf16_t*)Cp)[(size_t)row * N + col] = (bf16_t)v;
        } else {
          const int b = row >> 11, n = row & 2047;
          const int h = col >> 6, e = col & 63;
          ((bf16_t*)Cp)[(((size_t)((b << 4) + h) * 2048 + n) << 6) + e] = (bf16_t)v;
        }
      }
    }
  }
}

// K-split GEMM for MLP2 (grid.z selects K-half; fp32 partials, no bias).
__global__ __launch_bounds__(256) void gemm_bt_ksplit(
    const bf16_t* __restrict__ A, const bf16_t* __restrict__ Bw,
    float* __restrict__ C0, float* __restrict__ C1,
    int M, int N, int K, int Kh) {
  __shared__ bf16_t As[128 * 32];
  __shared__ bf16_t Bs[128 * 32];
  const int tid  = threadIdx.x;
  const int wave = tid >> 6, lane = tid & 63;
  const int quad = lane >> 4, l15 = lane & 15;
  const int m0 = blockIdx.x * 128, n0 = blockIdx.y * 128;
  const int wm = (wave >> 1) * 64, wn = (wave & 1) * 64;
  const int srow = wave * 32 + (lane >> 2);
  const int scol = (lane & 3) * 8;

  floatx4 acc[4][4] = {};

  const bf16_t* Ag = A  + (size_t)(m0 + srow) * K + scol;
  const bf16_t* Bg = Bw + (size_t)(n0 + srow) * K + scol;

  const int kbeg = blockIdx.z * Kh, kend = kbeg + Kh;
  for (int k0 = kbeg; k0 < kend; k0 += 32) {
    __syncthreads();
    #pragma unroll
    for (int i = 0; i < 2; ++i) {
      GLD_LDS(Ag + (size_t)(i * 16) * K + k0, As + wave * 1024 + i * 512);
      GLD_LDS(Bg + (size_t)(i * 16) * K + k0, Bs + wave * 1024 + i * 512);
    }
    __syncthreads();
    bf16x8 af[4], bfr[4];
    #pragma unroll
    for (int i = 0; i < 4; ++i)
      af[i] = *(const bf16x8*)(As + (wm + i * 16 + l15) * 32 + quad * 8);
    #pragma unroll
    for (int j = 0; j < 4; ++j)
      bfr[j] = *(const bf16x8*)(Bs + (wn + j * 16 + l15) * 32 + quad * 8);
    #pragma unroll
    for (int i = 0; i < 4; ++i)
      #pragma unroll
      for (int j = 0; j < 4; ++j)
        acc[i][j] = MFMA_BF16_16x16x32(af[i], bfr[j], acc[i][j], 0, 0, 0);
  }
  float* Cp = blockIdx.z ? C1 : C0;
  #pragma unroll
  for (int j = 0; j < 4; ++j) {
    const int col = n0 + wn + j * 16 + l15;
    #pragma unroll
    for (int i = 0; i < 4; ++i) {
      #pragma unroll
      for (int r = 0; r < 4; ++r) {
        const int row = m0 + wm + i * 16 + quad * 4 + r;
        Cp[(size_t)row * N + col] = acc[i][j][r];
      }
    }
  }
}

// out = a + b + bias  (fp32, row-major [4096,1024])
__global__ __launch_bounds__(256) void add2_bias(
    const float* __restrict__ a, const float* __restrict__ b,
    const float* __restrict__ bias, float* __restrict__ out) {
  const size_t row = blockIdx.x;
  const int c = threadIdx.x * 4;
  float4 va = *(const float4*)(a + row * 1024 + c);
  float4 vb = *(const float4*)(b + row * 1024 + c);
  float4 vc = *(const float4*)(bias + c);
  float4 o4;
  o4.x = va.x + vb.x + vc.x;
  o4.y = va.y + vb.y + vc.y;
  o4.z = va.z + vb.z + vc.z;
  o4.w = va.w + vb.w + vc.w;
  *(float4*)(out + row * 1024 + c) = o4;
}

// Split-precision GEMM for q,k: 3-term bf16 emulation of fp32.
// Writes q (cols<1024, scaled by 32=sqrt(D)) and k head-major, split hi/lo.
__global__ __launch_bounds__(256) void gemm_qk_split(
    const bf16_t* __restrict__ Ah, const bf16_t* __restrict__ Al,
    const bf16_t* __restrict__ Bh, const bf16_t* __restrict__ Bl,
    const float* __restrict__ bias,
    bf16_t* __restrict__ qhi, bf16_t* __restrict__ qlo,
    bf16_t* __restrict__ khi, bf16_t* __restrict__ klo,
    int M, int N, int K) {
  __shared__ bf16_t Ash[128 * 32];
  __shared__ bf16_t Asl[128 * 32];
  __shared__ bf16_t Bsh[128 * 32];
  __shared__ bf16_t Bsl[128 * 32];
  const int tid  = threadIdx.x;
  const int wave = tid >> 6, lane = tid & 63;
  const int quad = lane >> 4, l15 = lane & 15;
  const int m0 = blockIdx.x * 128, n0 = blockIdx.y * 128;
  const int wm = (wave >> 1) * 64, wn = (wave & 1) * 64;
  const int srow = wave * 32 + (lane >> 2);
  const int scol = (lane & 3) * 8;

  floatx4 acc[4][4] = {};

  const size_t aoff = (size_t)(m0 + srow) * K + scol;
  const size_t boff = (size_t)(n0 + srow) * K + scol;

  for (int k0 = 0; k0 < K; k0 += 32) {
    __syncthreads();
    #pragma unroll
    for (int i = 0; i < 2; ++i) {
      const size_t ga = aoff + (size_t)(i * 16) * K + k0;
      const size_t gb = boff + (size_t)(i * 16) * K + k0;
      GLD_LDS(Ah + ga, Ash + wave * 1024 + i * 512);
      GLD_LDS(Al + ga, Asl + wave * 1024 + i * 512);
      GLD_LDS(Bh + gb, Bsh + wave * 1024 + i * 512);
      GLD_LDS(Bl + gb, Bsl + wave * 1024 + i * 512);
    }
    __syncthreads();
    bf16x8 ah[4], al[4], bh[4], bl[4];
    #pragma unroll
    for (int i = 0; i < 4; ++i) {
      const int ro = (wm + i * 16 + l15) * 32 + quad * 8;
      ah[i] = *(const bf16x8*)(Ash + ro);
      al[i] = *(const bf16x8*)(Asl + ro);
    }
    #pragma unroll
    for (int j = 0; j < 4; ++j) {
      const int ro = (wn + j * 16 + l15) * 32 + quad * 8;
      bh[j] = *(const bf16x8*)(Bsh + ro);
      bl[j] = *(const bf16x8*)(Bsl + ro);
    }
    #pragma unroll
    for (int i = 0; i < 4; ++i)
      #pragma unroll
      for (int j = 0; j < 4; ++j) {
        acc[i][j] = MFMA_BF16_16x16x32(ah[i], bh[j], acc[i][j], 0, 0, 0);
        acc[i][j] = MFMA_BF16_16x16x32(ah[i], bl[j], acc[i][j], 0, 0, 0);
        acc[i][j] = MFMA_BF16_16x16x32(al[i], bh[j], acc[i][j], 0, 0, 0);
      }
  }
  #pragma unroll
  for (int j = 0; j < 4; ++j) {
    const int col = n0 + wn + j * 16 + l15;       // [0,2048)
    const float bv = bias[col];
    const bool isq = col < 1024;
    bf16_t* hib = isq ? qhi : khi;
    bf16_t* lob = isq ? qlo : klo;
    const float scale = isq ? 32.0f : 1.0f;       // sqrt(D) folded into q
    const int h = (col >> 6) & 15, e = col & 63;
    #pragma unroll
    for (int i = 0; i < 4; ++i) {
      #pragma unroll
      for (int r = 0; r < 4; ++r) {
        const int row = m0 + wm + i * 16 + quad * 4 + r;
        const int b = row >> 11, n = row & 2047;
        const float c = (acc[i][j][r] + bv) * scale;
        const bf16_t chi = (bf16_t)c;
        const bf16_t clo = (bf16_t)(c - (float)chi);
        const size_t dst = (((size_t)((b << 4) + h) * 2048 + n) << 6) + e;
        hib[dst] = chi;
        lob[dst] = clo;
      }
    }
  }
}

// ---------------- V transpose: [bh][n][64] -> [bh][e][2048] ----------------
__global__ __launch_bounds__(256) void transpose_v(
    const bf16_t* __restrict__ vhm, bf16_t* __restrict__ vT) {
  __shared__ bf16_t T[64 * 72];
  const int bh = blockIdx.x, n0 = blockIdx.y * 64;
  const int r = threadIdx.x >> 2;          // 0..63
  const int c = (threadIdx.x & 3) * 16;    // 0,16,32,48
  const bf16_t* src = vhm + ((size_t)bh * 2048 + n0 + r) * 64 + c;
  bf16x8 a0 = *(const bf16x8*)src;
  bf16x8 a1 = *(const bf16x8*)(src + 8);
  #pragma unroll
  for (int j = 0; j < 8; ++j) {
    T[(c + j) * 72 + r]     = a0[j];
    T[(c + 8 + j) * 72 + r] = a1[j];
  }
  __syncthreads();
  bf16x8 o0 = *(const bf16x8*)(T + r * 72 + c);
  bf16x8 o1 = *(const bf16x8*)(T + r * 72 + c + 8);
  bf16_t* dst = vT + ((size_t)(bh * 64 + r)) * 2048 + n0 + c;
  *(bf16x8*)dst = o0;
  *(bf16x8*)(dst + 8) = o1;
}

// ---------------- barrier-free causal flash attention ----------------
// 4 independent waves/block (no __syncthreads); wave owns 16 q-rows; TK=64.
// K/V consumed directly from global as MFMA B-fragments.
// GRID: bh = blockIdx.x (fastest) -> linear%8 = bh%8 -> each head pinned to
// one XCD; 4 heads x 768KB K/V fits the 4MB XCD-L2. (R10 transposed this and
// FETCH went 20.5->95.8 MB - measured XCD-thrash.) q heavy-first on y.
// Row max via 4x shfl; row sum via ones-MFMA. VGPR=64 (R10 counter) ->
// whole 1024-block grid co-resident (4 blocks/CU, 16 waves/CU).
__global__ __launch_bounds__(256) void attn_causal(
    const bf16_t* __restrict__ qhi, const bf16_t* __restrict__ qlo,
    const bf16_t* __restrict__ khi, const bf16_t* __restrict__ klo,
    const bf16_t* __restrict__ vT, float* __restrict__ o) {
  __shared__ bf16_t Ps[4][16 * 72];   // per-wave P: 16 rows x 64 cols, stride 72

  const int tid  = threadIdx.x;
  const int wave = tid >> 6, lane = tid & 63;
  const int quad = lane >> 4, l15 = lane & 15;
  const int bh = blockIdx.x;                    // head fastest: XCD = bh % 8
  const int q0 = (31 - (int)blockIdx.y) * 64;   // heavy q-tiles dispatch first
  const size_t hb = (size_t)bh * 2048;
  const int wmin = q0 + wave * 16;              // wave's 16 rows

  // Q fragments (A-layout: m=l15, k=quad*8+j)
  const bf16_t* qbh = qhi + ((hb + wmin + l15) << 6) + quad * 8;
  const bf16_t* qbl = qlo + ((hb + wmin + l15) << 6) + quad * 8;
  const bf16x8 qh0 = *(const bf16x8*)qbh, qh1 = *(const bf16x8*)(qbh + 32);
  const bf16x8 ql0 = *(const bf16x8*)qbl, ql1 = *(const bf16x8*)(qbl + 32);

  bf16x8 ones;
  #pragma unroll
  for (int j = 0; j < 8; ++j) ones[j] = (bf16_t)1.0f;

  floatx4 accO[4] = {};
  floatx4 accL = {};                            // row-sum accumulator
  float m_row[4] = {-1e30f, -1e30f, -1e30f, -1e30f};

  const int ntiles = (q0 >> 6) + 1;
  for (int t = 0; t < ntiles; ++t) {
    const int k0 = t * 64;
    const bool needmask = (k0 + 63 > wmin);

    // S = Q K^T; K B-frags straight from global (coalesced 16B/lane)
    floatx4 sv[4];
    #pragma unroll
    for (int jj = 0; jj < 4; ++jj) {
      const bf16_t* kbh = khi + ((hb + k0 + jj * 16 + l15) << 6) + quad * 8;
      const bf16_t* kbl = klo + ((hb + k0 + jj * 16 + l15) << 6) + quad * 8;
      const bf16x8 kh0 = *(const bf16x8*)kbh;
      const bf16x8 kh1 = *(const bf16x8*)(kbh + 32);
      const bf16x8 kl0 = *(const bf16x8*)kbl;
      const bf16x8 kl1 = *(const bf16x8*)(kbl + 32);
      floatx4 a = {};
      a = MFMA_BF16_16x16x32(qh0, kh0, a, 0, 0, 0);
      a = MFMA_BF16_16x16x32(qh1, kh1, a, 0, 0, 0);
      a = MFMA_BF16_16x16x32(qh0, kl0, a, 0, 0, 0);
      a = MFMA_BF16_16x16x32(qh1, kl1, a, 0, 0, 0);
      a = MFMA_BF16_16x16x32(ql0, kh0, a, 0, 0, 0);
      a = MFMA_BF16_16x16x32(ql1, kh1, a, 0, 0, 0);
      sv[jj] = a;
    }

    // online softmax; lane owns rows quad*4+r, cols jj*16+l15
    const int colb = k0 + l15;
    #pragma unroll
    for (int r = 0; r < 4; ++r) {
      const int rowg = wmin + quad * 4 + r;
      float sr[4], mr = -1e30f;
      #pragma unroll
      for (int jj = 0; jj < 4; ++jj) {
        float x = sv[jj][r];
        if (needmask && (colb + jj * 16 > rowg)) x = -1e30f;   // causal mask
        sr[jj] = x;
        mr = fmaxf(mr, x);
      }
      mr = fmaxf(mr, __shfl_xor(mr, 1));
      mr = fmaxf(mr, __shfl_xor(mr, 2));
      mr = fmaxf(mr, __shfl_xor(mr, 4));
      mr = fmaxf(mr, __shfl_xor(mr, 8));
      const float mnew = fmaxf(m_row[r], mr);
      const float alpha = __expf(m_row[r] - mnew);
      m_row[r] = mnew;
      #pragma unroll
      for (int jj = 0; jj < 4; ++jj)
        Ps[wave][(quad * 4 + r) * 72 + jj * 16 + l15] = (bf16_t)__expf(sr[jj] - mnew);
      #pragma unroll
      for (int j = 0; j < 4; ++j) accO[j][r] *= alpha;
      accL[r] *= alpha;
    }
    // Ps is wave-private: LDS completion is enough (no barrier in kernel)
    asm volatile("s_waitcnt lgkmcnt(0)" ::: "memory");

    // P A-frags (2 k-chunks of 32 keys)
    const bf16x8 pf0 = *(const bf16x8*)(&Ps[wave][l15 * 72 + quad * 8]);
    const bf16x8 pf1 = *(const bf16x8*)(&Ps[wave][l15 * 72 + 32 + quad * 8]);

    // row-sum via ones-MFMA (exactly matches bf16 P numerator)
    accL = MFMA_BF16_16x16x32(pf0, ones, accL, 0, 0, 0);
    accL = MFMA_BF16_16x16x32(pf1, ones, accL, 0, 0, 0);

    // O += P V  (V B-frags straight from vT global)
    #pragma unroll
    for (int j = 0; j < 4; ++j) {
      const bf16_t* vrow = vT + ((size_t)(bh * 64 + j * 16 + l15)) * 2048 + k0 + quad * 8;
      const bf16x8 vf0 = *(const bf16x8*)vrow;
      const bf16x8 vf1 = *(const bf16x8*)(vrow + 32);
      accO[j] = MFMA_BF16_16x16x32(pf0, vf0, accO[j], 0, 0, 0);
      accO[j] = MFMA_BF16_16x16x32(pf1, vf1, accO[j], 0, 0, 0);
    }
  }

  // normalize + write (token-major fp32 for resid_ln); accL[r] = l on all lanes
  const int b = bh >> 4, h = bh & 15;
  #pragma unroll
  for (int r = 0; r < 4; ++r) {
    const float linv = 1.f / accL[r];
    const int qr = wmin + quad * 4 + r;
    float* orow = o + ((size_t)(b * 2048) + qr) * 1024 + h * 64;
    #pragma unroll
    for (int j = 0; j < 4; ++j)
      orow[j * 16 + l15] = accO[j][r] * linv;
  }
}

// ---------------- launcher ----------------

extern "C" void kernel_launch(void* const* d_in, const int* in_sizes, int n_in,
                              void* d_out, int out_size, void* d_ws, size_t ws_size,
                              hipStream_t stream) {
  const float* x        = (const float*)d_in[0];
  const float* wq       = (const float*)d_in[1];
  const float* bq       = (const float*)d_in[2];
  const float* wk       = (const float*)d_in[3];
  const float* bk       = (const float*)d_in[4];
  const float* wv       = (const float*)d_in[5];
  const float* bv       = (const float*)d_in[6];
  const float* w1       = (const float*)d_in[7];
  const float* b1       = (const float*)d_in[8];
  const float* ln_mlp_g = (const float*)d_in[9];
  const float* ln_mlp_b = (const float*)d_in[10];
  const float* w2       = (const float*)d_in[11];
  const float* b2       = (const float*)d_in[12];
  const float* ln1_g    = (const float*)d_in[13];
  const float* ln1_b    = (const float*)d_in[14];
  const float* ln2_g    = (const float*)d_in[15];
  const float* ln2_b    = (const float*)d_in[16];

  // workspace layout (MiB offsets), aliased by phase lifetime:
  char* ws = (char*)d_ws;
  bf16_t* w1b    = (bf16_t*)(ws);                  // [0,8)
  bf16_t* w2b    = (bf16_t*)(ws + (8u   << 20));   // [8,16)
  bf16_t* qhi    = (bf16_t*)(ws + (16u  << 20));   // [16,24)
  bf16_t* qlo    = (bf16_t*)(ws + (24u  << 20));   // [24,32)
  bf16_t* khi    = (bf16_t*)(ws + (32u  << 20));   // [32,40)
  bf16_t* klo    = (bf16_t*)(ws + (40u  << 20));   // [40,48)
  bf16_t* mbuf   = (bf16_t*)(ws + (16u  << 20));   // [16,48)  (aliases q/k, dead by MLP1)
  bf16_t* wqk_hi = (bf16_t*)(ws + (48u  << 20));   // [48,52)
  bf16_t* wqk_lo = (bf16_t*)(ws + (52u  << 20));   // [52,56)
  bf16_t* vhm    = (bf16_t*)(ws + (48u  << 20));   // [48,56)  (aliases wqk, dead after qk gemm)
  bf16_t* wvb    = (bf16_t*)(ws + (56u  << 20));   // [56,58)
  float*  bqk    = (float*) (ws + (58u  << 20));   // [58,~)
  float*  attnb  = (float*) (ws + (48u  << 20));   // [48,64)  (aliases vhm/wvb/bqk, dead by attn)
  float*  part0  = (float*) (ws + (48u  << 20));   // [48,64)  (attnb dead by MLP2)
  bf16_t* h_hi   = (bf16_t*)(ws + (60u  << 20));   // [60,68)
  bf16_t* h_lo   = (bf16_t*)(ws + (68u  << 20));   // [68,76)
  bf16_t* h2     = (bf16_t*)(ws + (64u  << 20));   // [64,72)  (aliases h_lo, dead by resid_ln)
  bf16_t* vTb    = (bf16_t*)(ws + (76u  << 20));   // [76,84)
  float*  part1  = (float*) (ws + (84u  << 20));   // [84,100) (vTb dead by MLP2)

  prep<<<11268, 256, 0, stream>>>(wq, wk, wv, w1, w2, bq, bk,
                                  wqk_hi, wqk_lo, wvb, w1b, w2b, bqk);

  ln_fwd_split<<<4096, 256, 0, stream>>>(x, ln1_g, ln1_b, h_hi, h_lo);
  gemm_qk_split<<<dim3(32, 16), 256, 0, stream>>>(h_hi, h_lo, wqk_hi, wqk_lo, bqk,
                                                  qhi, qlo, khi, klo, 4096, 2048, 1024);
  gemm_bt<2><<<dim3(32, 8), 256, 0, stream>>>(h_hi, wvb, bv, vhm, 4096, 1024, 1024);
  transpose_v<<<dim3(32, 32), 256, 0, stream>>>(vhm, vTb);
  attn_causal<<<dim3(32, 32), 256, 0, stream>>>(qhi, qlo, khi, klo, vTb, attnb);
  resid_ln_fwd<<<4096, 256, 0, stream>>>(x, attnb, ln2_g, ln2_b, h2);
  gemm_bt<1><<<dim3(32, 32), 256, 0, stream>>>(h2, w1b, b1, mbuf, 4096, 4096, 1024);
  ln_relu_inplace<<<4096, 256, 0, stream>>>(mbuf, ln_mlp_g, ln_mlp_b);
  gemm_bt_ksplit<<<dim3(32, 8, 2), 256, 0, stream>>>(mbuf, w2b, part0, part1,
                                                     4096, 1024, 4096, 2048);
  add2_bias<<<4096, 256, 0, stream>>>(part0, part1, b2, (float*)d_out);

  (void)in_sizes; (void)n_in; (void)out_size; (void)ws_size;
}